// Round 2
// baseline (59.499 us; speedup 1.0000x reference)
//
#include <hip/hip_runtime.h>
#include <math.h>

#define HK 16
#define HV 32
#define DD 128
#define CC 8192          // D*(2*HK+HV)
#define EPSN 1e-6f
#define QSCALE 0.08838834764831845f   // 1/sqrt(128)

// -------------------- kernel 1: conv + silu + l2norm + gates --------------------
__global__ __launch_bounds__(256) void prep_kernel(
    const float* __restrict__ mixed_qkv,
    const float* __restrict__ a_in,
    const float* __restrict__ b_in,
    const float* __restrict__ conv_state,
    const float* __restrict__ conv_weights,
    const float* __restrict__ dt_bias,
    const float* __restrict__ A_log,
    float* __restrict__ ws_q, float* __restrict__ ws_k, float* __restrict__ ws_v,
    float* __restrict__ ws_g, float* __restrict__ ws_beta)
{
    const int b   = blockIdx.x;
    const int tid = threadIdx.x;
    __shared__ float xconv[CC];   // 32 KB

    const float* cs = conv_state + (size_t)b * 3 * CC;
    const float* mq = mixed_qkv  + (size_t)b * CC;

    for (int idx = tid; idx < CC; idx += 256) {
        float4 w = *reinterpret_cast<const float4*>(conv_weights + (size_t)idx * 4);
        float x = cs[idx] * w.x + cs[CC + idx] * w.y + cs[2 * CC + idx] * w.z
                + mq[idx] * w.w;
        xconv[idx] = x / (1.0f + expf(-x));   // silu
    }

    if (tid < HV) {
        float av = a_in[b * HV + tid] + dt_bias[tid];
        float sp = (av > 20.0f) ? av : log1pf(expf(av));   // softplus, overflow-safe
        ws_g[b * HV + tid]    = -expf(A_log[tid]) * sp;
        ws_beta[b * HV + tid] = 1.0f / (1.0f + expf(-b_in[b * HV + tid]));
    }
    __syncthreads();

    // l2norm: head h = tid>>3 (0..31: 0..15 -> q, 16..31 -> k), 8 threads/head
    const int h   = tid >> 3;
    const int sub = tid & 7;
    const float* base = xconv + h * DD;
    float ssq = 0.f;
    #pragma unroll
    for (int i = 0; i < 16; ++i) {
        float xv = base[sub + 8 * i];
        ssq += xv * xv;
    }
    ssq += __shfl_xor(ssq, 1);
    ssq += __shfl_xor(ssq, 2);
    ssq += __shfl_xor(ssq, 4);
    float r = rsqrtf(ssq + EPSN);
    float factor = (h < HK) ? r * QSCALE : r;
    float* dst = (h < HK) ? (ws_q + ((size_t)b * HK + h) * DD)
                          : (ws_k + ((size_t)b * HK + (h - HK)) * DD);
    #pragma unroll
    for (int i = 0; i < 16; ++i)
        dst[sub + 8 * i] = base[sub + 8 * i] * factor;

    // v passthrough (heads 32..63 of xconv)
    float* vdst = ws_v + (size_t)b * HV * DD;
    for (int idx = tid; idx < HV * DD; idx += 256)
        vdst[idx] = xconv[2 * HK * DD + idx];
}

// -------------------- kernel 2: state read + delta rule output --------------------
// out[v] = eg*dot(S0[v],q) + ((v[v] - eg*dot(S0[v],k)) * beta) * dot(k,q)
__global__ __launch_bounds__(256) void update_kernel(
    const float* __restrict__ ssm_state,
    const float* __restrict__ ws_q, const float* __restrict__ ws_k,
    const float* __restrict__ ws_v, const float* __restrict__ ws_g,
    const float* __restrict__ ws_beta,
    float* __restrict__ out)
{
    const int bh  = blockIdx.x;        // b*HV + h
    const int b   = bh >> 5;
    const int h   = bh & 31;
    const int qh  = h >> 1;            // repeat(rep=2): head h uses original h/2
    const int tid = threadIdx.x;
    const int col = (tid & 31) * 4;    // 4 contiguous cols per thread
    const int rb  = tid >> 5;          // 0..7

    __shared__ float dk[DD], dq[DD];

    const float4 kf = *reinterpret_cast<const float4*>(ws_k + ((size_t)b * HK + qh) * DD + col);
    const float4 qf = *reinterpret_cast<const float4*>(ws_q + ((size_t)b * HK + qh) * DD + col);

    // kq = dot(k,q); each aligned 32-lane group covers all 128 cols exactly once
    float kq = kf.x * qf.x + kf.y * qf.y + kf.z * qf.z + kf.w * qf.w;
    kq += __shfl_xor(kq, 16);
    kq += __shfl_xor(kq, 8);
    kq += __shfl_xor(kq, 4);
    kq += __shfl_xor(kq, 2);
    kq += __shfl_xor(kq, 1);

    const float* S = ssm_state + (size_t)bh * DD * DD;
    #pragma unroll
    for (int c = 0; c < 16; ++c) {
        const int row = c * 8 + rb;
        float4 s = *reinterpret_cast<const float4*>(S + (size_t)row * DD + col);
        float pk = s.x * kf.x + s.y * kf.y + s.z * kf.z + s.w * kf.w;
        float pq = s.x * qf.x + s.y * qf.y + s.z * qf.z + s.w * qf.w;
        #pragma unroll
        for (int m = 16; m >= 1; m >>= 1) {
            pk += __shfl_xor(pk, m);
            pq += __shfl_xor(pq, m);
        }
        if ((tid & 31) == 0) { dk[row] = pk; dq[row] = pq; }
    }
    __syncthreads();

    if (tid < DD) {
        float eg   = expf(ws_g[bh]);
        float beta = ws_beta[bh];
        float vv   = ws_v[(size_t)bh * DD + tid];
        float delta = (vv - eg * dk[tid]) * beta;
        out[(size_t)bh * DD + tid] = eg * dq[tid] + delta * kq;
    }
}

extern "C" void kernel_launch(void* const* d_in, const int* in_sizes, int n_in,
                              void* d_out, int out_size, void* d_ws, size_t ws_size,
                              hipStream_t stream) {
    const float* mixed_qkv    = (const float*)d_in[0];
    const float* a_in         = (const float*)d_in[1];
    const float* b_in         = (const float*)d_in[2];
    const float* conv_state   = (const float*)d_in[3];
    const float* ssm_state    = (const float*)d_in[4];
    const float* conv_weights = (const float*)d_in[5];
    const float* dt_bias      = (const float*)d_in[6];
    const float* A_log        = (const float*)d_in[7];
    float* out = (float*)d_out;

    const int B = in_sizes[1] / HV;   // a: (B, HV)

    float* ws_q    = (float*)d_ws;
    float* ws_k    = ws_q + (size_t)B * HK * DD;
    float* ws_v    = ws_k + (size_t)B * HK * DD;
    float* ws_g    = ws_v + (size_t)B * HV * DD;
    float* ws_beta = ws_g + (size_t)B * HV;

    prep_kernel<<<B, 256, 0, stream>>>(mixed_qkv, a_in, b_in, conv_state,
                                       conv_weights, dt_bias, A_log,
                                       ws_q, ws_k, ws_v, ws_g, ws_beta);
    update_kernel<<<B * HV, 256, 0, stream>>>(ssm_state, ws_q, ws_k, ws_v,
                                              ws_g, ws_beta, out);
}

// Round 3
// 48.980 us; speedup vs baseline: 1.2148x; 1.2148x over previous
//
#include <hip/hip_runtime.h>
#include <math.h>

#define HKn 16
#define HVn 32
#define DDn 128
#define CCn 8192          // D*(2*HK+HV)
#define EPSN 1e-6f
#define QSCALE 0.08838834764831845f   // 1/sqrt(128)

// One block per (b, h_v). Fully fused:
//  phase A: conv(K=4)+SiLU for the 3 relevant heads (q=h/2, k=16+h/2, v=32+h),
//           l2-norms + gates + kq, build combined vector w[c] = eg*(q[c] - beta*kq*k[c])
//  phase B: out[row] = sum_c S[row][c]*w[c]  (single streaming pass over 64KB state)
//  phase C: out[row] += beta*kq*v[row]
__global__ __launch_bounds__(256) void fused_gdn_decode(
    const float* __restrict__ mixed_qkv,
    const float* __restrict__ a_in,
    const float* __restrict__ b_in,
    const float* __restrict__ conv_state,
    const float* __restrict__ ssm_state,
    const float* __restrict__ conv_weights,
    const float* __restrict__ dt_bias,
    const float* __restrict__ A_log,
    float* __restrict__ out)
{
    const int bh = blockIdx.x;     // b*HV + h
    const int b  = bh >> 5;
    const int h  = bh & 31;
    const int qh = h >> 1;         // rep = HV/HK = 2
    const int t  = threadIdx.x;

    __shared__ float wv[DDn];      // combined weight vector (cols)
    __shared__ float vb[DDn];      // silu'd v
    __shared__ float po[DDn];      // per-row dot results
    __shared__ float red[6];       // 2 waves x {sum q^2, sum k^2, sum q*k}

    const float* cs = conv_state + (size_t)b * 3 * CCn;
    const float* mq = mixed_qkv  + (size_t)b * CCn;

    float xq = 0.f, xk = 0.f, bkq = 0.f;

    if (t < DDn) {
        // conv + silu for q-channel and k-channel
        const int cq = qh * DDn + t;
        const int ck = (HKn + qh) * DDn + t;
        float4 w = *reinterpret_cast<const float4*>(conv_weights + (size_t)cq * 4);
        float x = cs[cq] * w.x + cs[CCn + cq] * w.y + cs[2 * CCn + cq] * w.z + mq[cq] * w.w;
        xq = x / (1.f + expf(-x));
        w = *reinterpret_cast<const float4*>(conv_weights + (size_t)ck * 4);
        x = cs[ck] * w.x + cs[CCn + ck] * w.y + cs[2 * CCn + ck] * w.z + mq[ck] * w.w;
        xk = x / (1.f + expf(-x));

        float sqq = xq * xq, skk = xk * xk, sqk = xq * xk;
        #pragma unroll
        for (int m = 1; m <= 32; m <<= 1) {
            sqq += __shfl_xor(sqq, m);
            skk += __shfl_xor(skk, m);
            sqk += __shfl_xor(sqk, m);
        }
        if ((t & 63) == 0) {
            const int wv_ = t >> 6;
            red[wv_ * 3 + 0] = sqq;
            red[wv_ * 3 + 1] = skk;
            red[wv_ * 3 + 2] = sqk;
        }
    } else {
        // conv + silu for v-channel
        const int cv = (2 * HKn + h) * DDn + (t - DDn);
        float4 w = *reinterpret_cast<const float4*>(conv_weights + (size_t)cv * 4);
        float x = cs[cv] * w.x + cs[CCn + cv] * w.y + cs[2 * CCn + cv] * w.z + mq[cv] * w.w;
        vb[t - DDn] = x / (1.f + expf(-x));
    }
    __syncthreads();

    if (t < DDn) {
        const float sqq = red[0] + red[3];
        const float skk = red[1] + red[4];
        const float sqk = red[2] + red[5];
        const float rq = rsqrtf(sqq + EPSN);
        const float rk = rsqrtf(skk + EPSN);
        const float kq = QSCALE * rq * rk * sqk;          // dot(q_n, k_n)
        const float av = a_in[b * HVn + h] + dt_bias[h];
        const float sp = (av > 20.f) ? av : log1pf(expf(av));
        const float eg = expf(-expf(A_log[h]) * sp);
        const float beta = 1.f / (1.f + expf(-b_in[b * HVn + h]));
        bkq = beta * kq;
        wv[t] = eg * (rq * QSCALE * xq - bkq * rk * xk);
    }
    __syncthreads();

    // phase B: stream the 128x128 state, one dot(S[row], w) per row.
    // 16-lane groups: group g covers cols [0,128), thread owns 8 contiguous cols.
    const int colg = t & 15;
    const int rb   = t >> 4;           // 0..15
    const float4 w0 = *reinterpret_cast<const float4*>(&wv[colg * 8]);
    const float4 w1 = *reinterpret_cast<const float4*>(&wv[colg * 8 + 4]);
    const float* S = ssm_state + (size_t)bh * DDn * DDn;
    #pragma unroll
    for (int c = 0; c < 8; ++c) {
        const int row = c * 16 + rb;
        const float* Sr = S + (size_t)row * DDn + colg * 8;
        float4 s0 = *reinterpret_cast<const float4*>(Sr);
        float4 s1 = *reinterpret_cast<const float4*>(Sr + 4);
        float p = s0.x * w0.x + s0.y * w0.y + s0.z * w0.z + s0.w * w0.w
                + s1.x * w1.x + s1.y * w1.y + s1.z * w1.z + s1.w * w1.w;
        p += __shfl_xor(p, 8);
        p += __shfl_xor(p, 4);
        p += __shfl_xor(p, 2);
        p += __shfl_xor(p, 1);
        if (colg == 0) po[row] = p;
    }
    __syncthreads();

    if (t < DDn)
        out[(size_t)bh * DDn + t] = po[t] + bkq * vb[t];
}

extern "C" void kernel_launch(void* const* d_in, const int* in_sizes, int n_in,
                              void* d_out, int out_size, void* d_ws, size_t ws_size,
                              hipStream_t stream) {
    const float* mixed_qkv    = (const float*)d_in[0];
    const float* a_in         = (const float*)d_in[1];
    const float* b_in         = (const float*)d_in[2];
    const float* conv_state   = (const float*)d_in[3];
    const float* ssm_state    = (const float*)d_in[4];
    const float* conv_weights = (const float*)d_in[5];
    const float* dt_bias      = (const float*)d_in[6];
    const float* A_log        = (const float*)d_in[7];
    float* out = (float*)d_out;

    const int B = in_sizes[1] / HVn;   // a: (B, HV)

    fused_gdn_decode<<<B * HVn, 256, 0, stream>>>(
        mixed_qkv, a_in, b_in, conv_state, ssm_state,
        conv_weights, dt_bias, A_log, out);
}